// Round 2
// baseline (26127.020 us; speedup 1.0000x reference)
//
#include <hip/hip_runtime.h>

// LSTM: I=H=1024, B=64, S=512.
//   pack_wT:    transpose+convert 8 weight mats -> WiT[4096][1024], WhT[4096][1024] bf16
//   pack_misc:  bias[4096] = b_i*+b_h*; zero h ping-pong buffers + barrier counters
//   gemm_xproj: x_proj[32768][4096] BF16 = bf16-MFMA GEMM of x @ Wi  (bf16 store: ws fits)
//   lstm_scan:  persistent kernel, 256 blocks (4 groups x 64 slices), 512 steps,
//               Wh fragments register-resident, per-group atomic barrier per step.
// Workspace budget: 285,493,248 B total (guarded against ws_size).

typedef __bf16 bf16x8 __attribute__((ext_vector_type(8)));
typedef float f32x4 __attribute__((ext_vector_type(4)));

__device__ __forceinline__ unsigned short f2bf(float f) {
    unsigned int u = __float_as_uint(f);
    u = (u + 0x7FFFu + ((u >> 16) & 1u)) >> 16;
    return (unsigned short)u;
}
__device__ __forceinline__ float bf2f(unsigned short u) {
    return __uint_as_float((unsigned int)u << 16);
}

// ---------------------------------------------------------------------------
// Pack weights: out[n][k] = w[k][n&1023] for gate n>>10, bf16. 64x64 LDS transpose.
__global__ __launch_bounds__(256) void pack_wT(
    const float* __restrict__ w0, const float* __restrict__ w1,
    const float* __restrict__ w2, const float* __restrict__ w3,
    const float* __restrict__ w4, const float* __restrict__ w5,
    const float* __restrict__ w6, const float* __restrict__ w7,
    unsigned short* __restrict__ wiT, unsigned short* __restrict__ whT)
{
    __shared__ float tl[64][65];
    int bid = blockIdx.x;
    int mi = bid >> 8;          // 0..7: 0..3 = Wi gates i,f,g,o; 4..7 = Wh
    int tile = bid & 255;
    int tk = tile >> 4, tj = tile & 15;
    const float* w;
    int gate = mi & 3;
    if (mi < 4) w = (gate == 0) ? w0 : (gate == 1) ? w1 : (gate == 2) ? w2 : w3;
    else        w = (gate == 0) ? w4 : (gate == 1) ? w5 : (gate == 2) ? w6 : w7;
    unsigned short* out = (mi < 4) ? wiT : whT;
    int tx = threadIdx.x & 63, ty = threadIdx.x >> 6;
    #pragma unroll
    for (int i = 0; i < 16; i++) {
        int k = i * 4 + ty;
        tl[k][tx] = w[(long)(tk * 64 + k) * 1024 + tj * 64 + tx];
    }
    __syncthreads();
    #pragma unroll
    for (int i = 0; i < 16; i++) {
        int j = i * 4 + ty;
        out[(long)(gate * 1024 + tj * 64 + j) * 1024 + tk * 64 + tx] = f2bf(tl[tx][j]);
    }
}

// ---------------------------------------------------------------------------
__global__ __launch_bounds__(256) void pack_misc(
    const float* __restrict__ bi0, const float* __restrict__ bh0,
    const float* __restrict__ bi1, const float* __restrict__ bh1,
    const float* __restrict__ bi2, const float* __restrict__ bh2,
    const float* __restrict__ bi3, const float* __restrict__ bh3,
    float* __restrict__ bias, unsigned int* __restrict__ hbuf_u,
    unsigned int* __restrict__ counters)
{
    int idx = blockIdx.x * 256 + threadIdx.x;   // grid 256x256 = 65536
    hbuf_u[idx] = 0u;                            // 65536 u32 = 262144 B (both phases)
    if (idx < 4096) {
        int g = idx >> 10, j = idx & 1023;
        const float* bi = (g == 0) ? bi0 : (g == 1) ? bi1 : (g == 2) ? bi2 : bi3;
        const float* bh = (g == 0) ? bh0 : (g == 1) ? bh1 : (g == 2) ? bh2 : bh3;
        bias[idx] = bi[j] + bh[j];
    }
    if (idx < 8) counters[idx * 64] = 0u;        // 4 counters, 256B apart
}

// ---------------------------------------------------------------------------
// x_proj GEMM: C[32768][4096] bf16 = x[32768][1024] @ Wi[1024][4096], bf16 MFMA.
// 128x128 tile, BK=64, 4 waves in 2x2, each wave 4x4 MFMA tiles of 16x16x32.
__global__ __launch_bounds__(256, 2) void gemm_xproj(
    const float* __restrict__ x, const unsigned short* __restrict__ wiT,
    unsigned short* __restrict__ xp)
{
    __shared__ unsigned short sA[128 * 72];   // [m][k], stride 72 bf16 (pad 16B)
    __shared__ unsigned short sB[128 * 72];   // [n][k] (WiT already n-major)
    int bid = blockIdx.x;
    int mt = bid >> 5, nt = bid & 31;
    long m0 = (long)mt * 128;
    int n0 = nt * 128;
    int tid = threadIdx.x;
    int lane = tid & 63, wv = tid >> 6;
    int quad = lane >> 4, l15 = lane & 15;
    int wm = wv & 1, wn = wv >> 1;

    f32x4 acc[4][4];
    #pragma unroll
    for (int a = 0; a < 4; a++)
        #pragma unroll
        for (int b = 0; b < 4; b++)
            acc[a][b] = (f32x4){0.f, 0.f, 0.f, 0.f};

    for (int kb = 0; kb < 16; kb++) {
        int k0 = kb * 64;
        // stage A: 128x64 fp32 -> bf16 (8 float4 per thread)
        #pragma unroll
        for (int i = 0; i < 8; i++) {
            int ch = tid + i * 256;
            int row = ch >> 4, q = ch & 15;
            float4 v = *(const float4*)&x[(m0 + row) * 1024 + k0 + q * 4];
            uint2 p;
            p.x = (unsigned int)f2bf(v.x) | ((unsigned int)f2bf(v.y) << 16);
            p.y = (unsigned int)f2bf(v.z) | ((unsigned int)f2bf(v.w) << 16);
            *(uint2*)&sA[row * 72 + q * 4] = p;
        }
        // stage B: 128x64 bf16 (4 x 16B per thread)
        #pragma unroll
        for (int i = 0; i < 4; i++) {
            int ch = tid + i * 256;
            int row = ch >> 3, q = ch & 7;
            uint4 v = *(const uint4*)&wiT[(long)(n0 + row) * 1024 + k0 + q * 8];
            *(uint4*)&sB[row * 72 + q * 8] = v;
        }
        __syncthreads();
        #pragma unroll
        for (int ks = 0; ks < 2; ks++) {
            bf16x8 af[4], bfr[4];
            #pragma unroll
            for (int mi2 = 0; mi2 < 4; mi2++)
                af[mi2] = *(const bf16x8*)&sA[(wm * 64 + mi2 * 16 + l15) * 72 + ks * 32 + quad * 8];
            #pragma unroll
            for (int ni = 0; ni < 4; ni++)
                bfr[ni] = *(const bf16x8*)&sB[(wn * 64 + ni * 16 + l15) * 72 + ks * 32 + quad * 8];
            #pragma unroll
            for (int mi2 = 0; mi2 < 4; mi2++)
                #pragma unroll
                for (int ni = 0; ni < 4; ni++)
                    acc[mi2][ni] = __builtin_amdgcn_mfma_f32_16x16x32_bf16(
                        af[mi2], bfr[ni], acc[mi2][ni], 0, 0, 0);
        }
        __syncthreads();
    }
    // epilogue: C rows = quad*4+r, cols = l15 (verified m89 layout); bf16 store
    #pragma unroll
    for (int mi2 = 0; mi2 < 4; mi2++)
        #pragma unroll
        for (int ni = 0; ni < 4; ni++)
            #pragma unroll
            for (int r = 0; r < 4; r++) {
                long row = m0 + wm * 64 + mi2 * 16 + quad * 4 + r;
                int col = n0 + wn * 64 + ni * 16 + l15;
                xp[row * 4096 + col] = f2bf(acc[mi2][ni][r]);
            }
}

// ---------------------------------------------------------------------------
// Persistent LSTM scan. 256 blocks x 256 threads.
// block = (group g = bid/64 -> batch rows 16g..16g+15, slice s = bid%64 -> h cols 16s..)
// wave w = gate w (i,f,g,o). Wh B-fragments register-resident (128 VGPRs/lane).
__global__ __launch_bounds__(256, 2) void lstm_scan(
    const unsigned short* __restrict__ xp, const unsigned short* __restrict__ whT,
    const float* __restrict__ bias, unsigned short* __restrict__ hbuf,
    unsigned int* __restrict__ counters, float* __restrict__ out)
{
    __shared__ unsigned short hl[16 * 1032];  // h tile [16][1024], stride 1032 (pad 16B)
    __shared__ float xch[4][16][16];          // gate exchange

    int bid = blockIdx.x;
    int g = bid >> 6, s = bid & 63;
    int tid = threadIdx.x;
    int lane = tid & 63, wv = tid >> 6;
    int quad = lane >> 4, l15 = lane & 15;

    // preload Wh fragments: B[k=kk*32+quad*8+j][n=l15] from WhT row (gate,col)
    bf16x8 bfrag[32];
    {
        const unsigned short* bp = whT + (long)(wv * 1024 + s * 16 + l15) * 1024 + quad * 8;
        #pragma unroll
        for (int kk = 0; kk < 32; kk++)
            bfrag[kk] = *(const bf16x8*)(bp + kk * 32);
    }

    int row = tid >> 4, col = tid & 15;       // elementwise ownership (batch-local, h-col-local)
    float b4[4];
    #pragma unroll
    for (int gg = 0; gg < 4; gg++) b4[gg] = bias[gg * 1024 + s * 16 + col];

    float c = 0.f;
    unsigned int* cnt = counters + g * 64;
    unsigned short* hb0 = hbuf + g * 16 * 1024;                 // phase 0 (zeroed = h(0))
    unsigned short* hb1 = hbuf + 4 * 16 * 1024 + g * 16 * 1024; // phase 1

    for (int t = 0; t < 512; t++) {
        // prefetch x_proj gate values for this thread's (batch,col), bf16
        const unsigned short* xrow = xp + ((long)(g * 16 + row) * 512 + t) * 4096 + s * 16 + col;
        float xpi = bf2f(xrow[0]);
        float xpf = bf2f(xrow[1024]);
        float xpg = bf2f(xrow[2048]);
        float xpo = bf2f(xrow[3072]);

        // stage h(t) 32KB -> LDS (8 x 16B per thread, coalesced)
        const unsigned short* hsrc = (t & 1) ? hb1 : hb0;
        #pragma unroll
        for (int i = 0; i < 8; i++) {
            int ch = tid + i * 256;
            int r2 = ch >> 7, o16 = ch & 127;
            uint4 v = *(const uint4*)(hsrc + r2 * 1024 + o16 * 8);
            *(uint4*)&hl[r2 * 1032 + o16 * 8] = v;
        }
        __syncthreads();

        // gates tile for this wave's gate: 16x16, K=1024
        f32x4 acc = {0.f, 0.f, 0.f, 0.f};
        #pragma unroll
        for (int kk = 0; kk < 32; kk++) {
            bf16x8 af = *(const bf16x8*)&hl[l15 * 1032 + kk * 32 + quad * 8];
            acc = __builtin_amdgcn_mfma_f32_16x16x32_bf16(af, bfrag[kk], acc, 0, 0, 0);
        }
        #pragma unroll
        for (int r = 0; r < 4; r++)
            xch[wv][quad * 4 + r][l15] = acc[r];
        __syncthreads();

        // elementwise LSTM cell (one (batch,col) per thread, c fp32-resident)
        float gi = xch[0][row][col] + xpi + b4[0];
        float gf = xch[1][row][col] + xpf + b4[1];
        float gg_ = xch[2][row][col] + xpg + b4[2];
        float go = xch[3][row][col] + xpo + b4[3];
        float iv = 1.f / (1.f + __expf(-gi));
        float fv = 1.f / (1.f + __expf(-gf));
        float gv = 1.f - 2.f / (__expf(2.f * gg_) + 1.f);   // tanh
        float ov = 1.f / (1.f + __expf(-go));
        c = c * fv + iv * gv;
        float h = ov * (1.f - 2.f / (__expf(2.f * c) + 1.f));

        unsigned short* hdst = (t & 1) ? hb0 : hb1;
        hdst[row * 1024 + s * 16 + col] = f2bf(h);

        if (t == 511) {
            out[(g * 16 + row) * 1024 + s * 16 + col] = h;
            out[65536 + (g * 16 + row) * 1024 + s * 16 + col] = c;
        } else {
            // per-group barrier: publish h slice, wait for all 64 WGs of the group
            __threadfence();          // release our h stores (agent scope)
            __syncthreads();
            if (tid == 0) {
                __hip_atomic_fetch_add(cnt, 1u, __ATOMIC_ACQ_REL, __HIP_MEMORY_SCOPE_AGENT);
                unsigned int target = 64u * (unsigned int)(t + 1);
                while (__hip_atomic_load(cnt, __ATOMIC_ACQUIRE, __HIP_MEMORY_SCOPE_AGENT) < target)
                    __builtin_amdgcn_s_sleep(2);
            }
            __syncthreads();
            __threadfence();          // acquire side before reading other WGs' h
        }
    }
}

// ---------------------------------------------------------------------------
extern "C" void kernel_launch(void* const* d_in, const int* in_sizes, int n_in,
                              void* d_out, int out_size, void* d_ws, size_t ws_size,
                              hipStream_t stream)
{
    const float* x    = (const float*)d_in[0];
    const float* w_ii = (const float*)d_in[1];
    const float* b_ii = (const float*)d_in[2];
    const float* w_hi = (const float*)d_in[3];
    const float* b_hi = (const float*)d_in[4];
    const float* w_if = (const float*)d_in[5];
    const float* b_if = (const float*)d_in[6];
    const float* w_hf = (const float*)d_in[7];
    const float* b_hf = (const float*)d_in[8];
    const float* w_ig = (const float*)d_in[9];
    const float* b_ig = (const float*)d_in[10];
    const float* w_hg = (const float*)d_in[11];
    const float* b_hg = (const float*)d_in[12];
    const float* w_io = (const float*)d_in[13];
    const float* b_io = (const float*)d_in[14];
    const float* w_ho = (const float*)d_in[15];
    const float* b_ho = (const float*)d_in[16];

    // Workspace layout (bf16 x_proj). Total = 285,493,248 B.
    const size_t OFF_XPJ  = 0;                       // 268,435,456 B (32768*4096*2)
    const size_t OFF_WIT  = 268435456;               //   8,388,608 B
    const size_t OFF_WHT  = 276824064;               //   8,388,608 B
    const size_t OFF_BIAS = 285212672;               //      16,384 B
    const size_t OFF_HBUF = 285229056;               //     262,144 B
    const size_t OFF_CNT  = 285491200;               //       2,048 B
    const size_t NEEDED   = 285493248;
    if (ws_size < NEEDED) return;  // diagnostic: clean absmax-fail instead of OOB crash

    char* ws = (char*)d_ws;
    unsigned short* xpj      = (unsigned short*)(ws + OFF_XPJ);
    unsigned short* wiT      = (unsigned short*)(ws + OFF_WIT);
    unsigned short* whT      = (unsigned short*)(ws + OFF_WHT);
    float*          bias     = (float*)(ws + OFF_BIAS);
    unsigned short* hbuf     = (unsigned short*)(ws + OFF_HBUF);
    unsigned int*   counters = (unsigned int*)(ws + OFF_CNT);

    pack_wT<<<2048, 256, 0, stream>>>(w_ii, w_if, w_ig, w_io,
                                      w_hi, w_hf, w_hg, w_ho, wiT, whT);
    pack_misc<<<256, 256, 0, stream>>>(b_ii, b_hi, b_if, b_hf, b_ig, b_hg, b_io, b_ho,
                                       bias, (unsigned int*)hbuf, counters);
    gemm_xproj<<<8192, 256, 0, stream>>>(x, wiT, xpj);
    lstm_scan<<<256, 256, 0, stream>>>(xpj, whT, bias, hbuf, counters, (float*)d_out);
}

// Round 3
// 5550.238 us; speedup vs baseline: 4.7074x; 4.7074x over previous
//
#include <hip/hip_runtime.h>

// LSTM: I=H=1024, B=64, S=512.
//   pack_wT:    transpose+convert 8 weight mats -> WiT[4096][1024], WhT[4096][1024] bf16
//   pack_misc:  bias[4096] = b_i*+b_h*; zero h ping-pong buffers + barrier counters
//   gemm_xproj: x_proj[32768][4096] BF16 = bf16-MFMA GEMM of x @ Wi
//   lstm_scan:  persistent kernel, 256 blocks (4 groups x 64 slices), 512 steps.
//               Round-3 change: NO __threadfence (agent fences = full L2 wbl2/inv walk,
//               ~50us/step). h exchange is write-through sc0sc1 atomics + MALL-bypass
//               loads; barrier is relaxed-agent atomic counter; __syncthreads drains.
// Workspace budget: 285,493,248 B total (guarded against ws_size).

typedef __bf16 bf16x8 __attribute__((ext_vector_type(8)));
typedef float f32x4 __attribute__((ext_vector_type(4)));

__device__ __forceinline__ unsigned short f2bf(float f) {
    unsigned int u = __float_as_uint(f);
    u = (u + 0x7FFFu + ((u >> 16) & 1u)) >> 16;
    return (unsigned short)u;
}
__device__ __forceinline__ float bf2f(unsigned short u) {
    return __uint_as_float((unsigned int)u << 16);
}

// ---------------------------------------------------------------------------
// Pack weights: out[n][k] = w[k][n&1023] for gate n>>10, bf16. 64x64 LDS transpose.
__global__ __launch_bounds__(256) void pack_wT(
    const float* __restrict__ w0, const float* __restrict__ w1,
    const float* __restrict__ w2, const float* __restrict__ w3,
    const float* __restrict__ w4, const float* __restrict__ w5,
    const float* __restrict__ w6, const float* __restrict__ w7,
    unsigned short* __restrict__ wiT, unsigned short* __restrict__ whT)
{
    __shared__ float tl[64][65];
    int bid = blockIdx.x;
    int mi = bid >> 8;          // 0..7: 0..3 = Wi gates i,f,g,o; 4..7 = Wh
    int tile = bid & 255;
    int tk = tile >> 4, tj = tile & 15;
    const float* w;
    int gate = mi & 3;
    if (mi < 4) w = (gate == 0) ? w0 : (gate == 1) ? w1 : (gate == 2) ? w2 : w3;
    else        w = (gate == 0) ? w4 : (gate == 1) ? w5 : (gate == 2) ? w6 : w7;
    unsigned short* out = (mi < 4) ? wiT : whT;
    int tx = threadIdx.x & 63, ty = threadIdx.x >> 6;
    #pragma unroll
    for (int i = 0; i < 16; i++) {
        int k = i * 4 + ty;
        tl[k][tx] = w[(long)(tk * 64 + k) * 1024 + tj * 64 + tx];
    }
    __syncthreads();
    #pragma unroll
    for (int i = 0; i < 16; i++) {
        int j = i * 4 + ty;
        out[(long)(gate * 1024 + tj * 64 + j) * 1024 + tk * 64 + tx] = f2bf(tl[tx][j]);
    }
}

// ---------------------------------------------------------------------------
__global__ __launch_bounds__(256) void pack_misc(
    const float* __restrict__ bi0, const float* __restrict__ bh0,
    const float* __restrict__ bi1, const float* __restrict__ bh1,
    const float* __restrict__ bi2, const float* __restrict__ bh2,
    const float* __restrict__ bi3, const float* __restrict__ bh3,
    float* __restrict__ bias, unsigned int* __restrict__ hbuf_u,
    unsigned int* __restrict__ counters)
{
    int idx = blockIdx.x * 256 + threadIdx.x;   // grid 256x256 = 65536
    hbuf_u[idx] = 0u;                            // 65536 u32 = 262144 B (both phases)
    if (idx < 4096) {
        int g = idx >> 10, j = idx & 1023;
        const float* bi = (g == 0) ? bi0 : (g == 1) ? bi1 : (g == 2) ? bi2 : bi3;
        const float* bh = (g == 0) ? bh0 : (g == 1) ? bh1 : (g == 2) ? bh2 : bh3;
        bias[idx] = bi[j] + bh[j];
    }
    if (idx < 8) counters[idx * 64] = 0u;        // 4 counters, 256B apart
}

// ---------------------------------------------------------------------------
// x_proj GEMM: C[32768][4096] bf16 = x[32768][1024] @ Wi[1024][4096], bf16 MFMA.
// 128x128 tile, BK=64, 4 waves in 2x2, each wave 4x4 MFMA tiles of 16x16x32.
__global__ __launch_bounds__(256, 2) void gemm_xproj(
    const float* __restrict__ x, const unsigned short* __restrict__ wiT,
    unsigned short* __restrict__ xp)
{
    __shared__ unsigned short sA[128 * 72];   // [m][k], stride 72 bf16 (pad 16B)
    __shared__ unsigned short sB[128 * 72];   // [n][k] (WiT already n-major)
    int bid = blockIdx.x;
    int mt = bid >> 5, nt = bid & 31;
    long m0 = (long)mt * 128;
    int n0 = nt * 128;
    int tid = threadIdx.x;
    int lane = tid & 63, wv = tid >> 6;
    int quad = lane >> 4, l15 = lane & 15;
    int wm = wv & 1, wn = wv >> 1;

    f32x4 acc[4][4];
    #pragma unroll
    for (int a = 0; a < 4; a++)
        #pragma unroll
        for (int b = 0; b < 4; b++)
            acc[a][b] = (f32x4){0.f, 0.f, 0.f, 0.f};

    for (int kb = 0; kb < 16; kb++) {
        int k0 = kb * 64;
        // stage A: 128x64 fp32 -> bf16 (8 float4 per thread)
        #pragma unroll
        for (int i = 0; i < 8; i++) {
            int ch = tid + i * 256;
            int row = ch >> 4, q = ch & 15;
            float4 v = *(const float4*)&x[(m0 + row) * 1024 + k0 + q * 4];
            uint2 p;
            p.x = (unsigned int)f2bf(v.x) | ((unsigned int)f2bf(v.y) << 16);
            p.y = (unsigned int)f2bf(v.z) | ((unsigned int)f2bf(v.w) << 16);
            *(uint2*)&sA[row * 72 + q * 4] = p;
        }
        // stage B: 128x64 bf16 (4 x 16B per thread)
        #pragma unroll
        for (int i = 0; i < 4; i++) {
            int ch = tid + i * 256;
            int row = ch >> 3, q = ch & 7;
            uint4 v = *(const uint4*)&wiT[(long)(n0 + row) * 1024 + k0 + q * 8];
            *(uint4*)&sB[row * 72 + q * 8] = v;
        }
        __syncthreads();
        #pragma unroll
        for (int ks = 0; ks < 2; ks++) {
            bf16x8 af[4], bfr[4];
            #pragma unroll
            for (int mi2 = 0; mi2 < 4; mi2++)
                af[mi2] = *(const bf16x8*)&sA[(wm * 64 + mi2 * 16 + l15) * 72 + ks * 32 + quad * 8];
            #pragma unroll
            for (int ni = 0; ni < 4; ni++)
                bfr[ni] = *(const bf16x8*)&sB[(wn * 64 + ni * 16 + l15) * 72 + ks * 32 + quad * 8];
            #pragma unroll
            for (int mi2 = 0; mi2 < 4; mi2++)
                #pragma unroll
                for (int ni = 0; ni < 4; ni++)
                    acc[mi2][ni] = __builtin_amdgcn_mfma_f32_16x16x32_bf16(
                        af[mi2], bfr[ni], acc[mi2][ni], 0, 0, 0);
        }
        __syncthreads();
    }
    // epilogue: C rows = quad*4+r, cols = l15 (verified m89 layout); bf16 store
    #pragma unroll
    for (int mi2 = 0; mi2 < 4; mi2++)
        #pragma unroll
        for (int ni = 0; ni < 4; ni++)
            #pragma unroll
            for (int r = 0; r < 4; r++) {
                long row = m0 + wm * 64 + mi2 * 16 + quad * 4 + r;
                int col = n0 + wn * 64 + ni * 16 + l15;
                xp[row * 4096 + col] = f2bf(acc[mi2][ni][r]);
            }
}

// ---------------------------------------------------------------------------
// Persistent LSTM scan. 256 blocks x 256 threads.
// block = (group g = bid/64 -> batch rows 16g..16g+15, slice s = bid%64 -> h cols 16s..)
// wave w = gate w (i,f,g,o). Wh B-fragments register-resident.
// NO agent fences in the loop: h goes through write-through (sc0 sc1) atomic stores
// and cache-bypassing atomic loads; visibility point is the MALL.
__global__ __launch_bounds__(256, 2) void lstm_scan(
    const unsigned short* __restrict__ xp, const unsigned short* __restrict__ whT,
    const float* __restrict__ bias, unsigned short* __restrict__ hbuf,
    unsigned int* __restrict__ counters, float* __restrict__ out)
{
    __shared__ unsigned short hl[16 * 1032];  // h tile [16][1024], stride 1032 (pad 16B)
    __shared__ float xch[4][16][16];          // gate exchange

    int bid = blockIdx.x;
    int g = bid >> 6, s = bid & 63;
    int tid = threadIdx.x;
    int lane = tid & 63, wv = tid >> 6;
    int quad = lane >> 4, l15 = lane & 15;

    // preload Wh fragments: B[k=kk*32+quad*8+j][n=l15] from WhT row (gate,col)
    bf16x8 bfrag[32];
    {
        const unsigned short* bp = whT + (long)(wv * 1024 + s * 16 + l15) * 1024 + quad * 8;
        #pragma unroll
        for (int kk = 0; kk < 32; kk++)
            bfrag[kk] = *(const bf16x8*)(bp + kk * 32);
    }

    int row = tid >> 4, col = tid & 15;       // elementwise ownership (batch-local, h-col-local)
    float b4[4];
    #pragma unroll
    for (int gg = 0; gg < 4; gg++) b4[gg] = bias[gg * 1024 + s * 16 + col];

    float c = 0.f;
    unsigned int* cnt = counters + g * 64;
    unsigned short* hb0 = hbuf + g * 16 * 1024;                 // phase 0 (zeroed = h(0))
    unsigned short* hb1 = hbuf + 4 * 16 * 1024 + g * 16 * 1024; // phase 1

    for (int t = 0; t < 512; t++) {
        // prefetch x_proj gate values for this thread's (batch,col), bf16 (normal cached)
        const unsigned short* xrow = xp + ((long)(g * 16 + row) * 512 + t) * 4096 + s * 16 + col;
        float xpi = bf2f(xrow[0]);
        float xpf = bf2f(xrow[1024]);
        float xpg = bf2f(xrow[2048]);
        float xpo = bf2f(xrow[3072]);

        // stage h(t) 32KB -> LDS via cache-bypassing u32 loads (32 per thread, coalesced)
        const unsigned int* hsrc32 = (const unsigned int*)((t & 1) ? hb1 : hb0);
        #pragma unroll
        for (int i = 0; i < 32; i++) {
            int ch = tid + i * 256;
            int r2 = ch >> 9, off = ch & 511;          // 512 u32 per row
            unsigned int v = __hip_atomic_load(hsrc32 + r2 * 512 + off,
                                               __ATOMIC_RELAXED, __HIP_MEMORY_SCOPE_AGENT);
            *(unsigned int*)&hl[r2 * 1032 + off * 2] = v;
        }
        __syncthreads();

        // gates tile for this wave's gate: 16x16, K=1024
        f32x4 acc = {0.f, 0.f, 0.f, 0.f};
        #pragma unroll
        for (int kk = 0; kk < 32; kk++) {
            bf16x8 af = *(const bf16x8*)&hl[l15 * 1032 + kk * 32 + quad * 8];
            acc = __builtin_amdgcn_mfma_f32_16x16x32_bf16(af, bfrag[kk], acc, 0, 0, 0);
        }
        #pragma unroll
        for (int r = 0; r < 4; r++)
            xch[wv][quad * 4 + r][l15] = acc[r];
        __syncthreads();

        // elementwise LSTM cell (one (batch,col) per thread, c fp32-resident)
        float gi = xch[0][row][col] + xpi + b4[0];
        float gf = xch[1][row][col] + xpf + b4[1];
        float gg_ = xch[2][row][col] + xpg + b4[2];
        float go = xch[3][row][col] + xpo + b4[3];
        float iv = 1.f / (1.f + __expf(-gi));
        float fv = 1.f / (1.f + __expf(-gf));
        float gv = 1.f - 2.f / (__expf(2.f * gg_) + 1.f);   // tanh
        float ov = 1.f / (1.f + __expf(-go));
        c = c * fv + iv * gv;
        float h = ov * (1.f - 2.f / (__expf(2.f * c) + 1.f));

        if (t == 511) {
            out[(g * 16 + row) * 1024 + s * 16 + col] = h;
            out[65536 + (g * 16 + row) * 1024 + s * 16 + col] = c;
        } else {
            // publish h slice write-through (sc0 sc1): visible at MALL once retired
            unsigned short* hdst = (t & 1) ? hb0 : hb1;
            __hip_atomic_store(&hdst[row * 1024 + s * 16 + col], f2bf(h),
                               __ATOMIC_RELAXED, __HIP_MEMORY_SCOPE_AGENT);
            // per-group barrier: __syncthreads drains each wave's stores (s_waitcnt
            // vmcnt(0) before s_barrier), so arrival implies our h is at the MALL.
            __syncthreads();
            if (tid == 0) {
                __hip_atomic_fetch_add(cnt, 1u, __ATOMIC_RELAXED, __HIP_MEMORY_SCOPE_AGENT);
                unsigned int target = 64u * (unsigned int)(t + 1);
                while (__hip_atomic_load(cnt, __ATOMIC_RELAXED, __HIP_MEMORY_SCOPE_AGENT) < target)
                    __builtin_amdgcn_s_sleep(2);
            }
            __syncthreads();
        }
    }
}

// ---------------------------------------------------------------------------
extern "C" void kernel_launch(void* const* d_in, const int* in_sizes, int n_in,
                              void* d_out, int out_size, void* d_ws, size_t ws_size,
                              hipStream_t stream)
{
    const float* x    = (const float*)d_in[0];
    const float* w_ii = (const float*)d_in[1];
    const float* b_ii = (const float*)d_in[2];
    const float* w_hi = (const float*)d_in[3];
    const float* b_hi = (const float*)d_in[4];
    const float* w_if = (const float*)d_in[5];
    const float* b_if = (const float*)d_in[6];
    const float* w_hf = (const float*)d_in[7];
    const float* b_hf = (const float*)d_in[8];
    const float* w_ig = (const float*)d_in[9];
    const float* b_ig = (const float*)d_in[10];
    const float* w_hg = (const float*)d_in[11];
    const float* b_hg = (const float*)d_in[12];
    const float* w_io = (const float*)d_in[13];
    const float* b_io = (const float*)d_in[14];
    const float* w_ho = (const float*)d_in[15];
    const float* b_ho = (const float*)d_in[16];

    // Workspace layout (bf16 x_proj). Total = 285,493,248 B.
    const size_t OFF_XPJ  = 0;                       // 268,435,456 B (32768*4096*2)
    const size_t OFF_WIT  = 268435456;               //   8,388,608 B
    const size_t OFF_WHT  = 276824064;               //   8,388,608 B
    const size_t OFF_BIAS = 285212672;               //      16,384 B
    const size_t OFF_HBUF = 285229056;               //     262,144 B
    const size_t OFF_CNT  = 285491200;               //       2,048 B
    const size_t NEEDED   = 285493248;
    if (ws_size < NEEDED) return;  // diagnostic: clean absmax-fail instead of OOB crash

    char* ws = (char*)d_ws;
    unsigned short* xpj      = (unsigned short*)(ws + OFF_XPJ);
    unsigned short* wiT      = (unsigned short*)(ws + OFF_WIT);
    unsigned short* whT      = (unsigned short*)(ws + OFF_WHT);
    float*          bias     = (float*)(ws + OFF_BIAS);
    unsigned short* hbuf     = (unsigned short*)(ws + OFF_HBUF);
    unsigned int*   counters = (unsigned int*)(ws + OFF_CNT);

    pack_wT<<<2048, 256, 0, stream>>>(w_ii, w_if, w_ig, w_io,
                                      w_hi, w_hf, w_hg, w_ho, wiT, whT);
    pack_misc<<<256, 256, 0, stream>>>(b_ii, b_hi, b_if, b_hf, b_ig, b_hg, b_io, b_ho,
                                       bias, (unsigned int*)hbuf, counters);
    gemm_xproj<<<8192, 256, 0, stream>>>(x, wiT, xpj);
    lstm_scan<<<256, 256, 0, stream>>>(xpj, whT, bias, hbuf, counters, (float*)d_out);
}

// Round 4
// 2376.653 us; speedup vs baseline: 10.9932x; 2.3353x over previous
//
#include <hip/hip_runtime.h>

// LSTM: I=H=1024, B=64, S=512.
//   pack_wT:    transpose+convert 8 weight mats -> WiT[4096][1024], WhT[4096][1024] bf16
//   pack_misc:  bias[4096] = b_i*+b_h*; zero h ping-pong buffers + epoch flags
//   gemm_xproj: x_proj bf16, gate-interleaved layout [b][t][h][gate]
//   lstm_scan:  persistent, 256 blocks (4 groups x 64 slices), 512 steps.
//               R3: no agent fences (write-through sc0sc1 + bypass loads).
//               R4: flag-array barrier (no atomic contention, 1 less barrier),
//                   16B asm staging loads, 1x8B gate-interleaved xp read.
// Workspace: 285,493,248 B (guarded).

typedef __bf16 bf16x8 __attribute__((ext_vector_type(8)));
typedef float f32x4 __attribute__((ext_vector_type(4)));
typedef unsigned int uint4v __attribute__((ext_vector_type(4)));

__device__ __forceinline__ unsigned short f2bf(float f) {
    unsigned int u = __float_as_uint(f);
    u = (u + 0x7FFFu + ((u >> 16) & 1u)) >> 16;
    return (unsigned short)u;
}
__device__ __forceinline__ float bf2f(unsigned short u) {
    return __uint_as_float((unsigned int)u << 16);
}

// ---------------------------------------------------------------------------
// Pack weights: out[n][k] = w[k][n&1023] for gate n>>10, bf16. 64x64 LDS transpose.
__global__ __launch_bounds__(256) void pack_wT(
    const float* __restrict__ w0, const float* __restrict__ w1,
    const float* __restrict__ w2, const float* __restrict__ w3,
    const float* __restrict__ w4, const float* __restrict__ w5,
    const float* __restrict__ w6, const float* __restrict__ w7,
    unsigned short* __restrict__ wiT, unsigned short* __restrict__ whT)
{
    __shared__ float tl[64][65];
    int bid = blockIdx.x;
    int mi = bid >> 8;          // 0..7: 0..3 = Wi gates i,f,g,o; 4..7 = Wh
    int tile = bid & 255;
    int tk = tile >> 4, tj = tile & 15;
    const float* w;
    int gate = mi & 3;
    if (mi < 4) w = (gate == 0) ? w0 : (gate == 1) ? w1 : (gate == 2) ? w2 : w3;
    else        w = (gate == 0) ? w4 : (gate == 1) ? w5 : (gate == 2) ? w6 : w7;
    unsigned short* out = (mi < 4) ? wiT : whT;
    int tx = threadIdx.x & 63, ty = threadIdx.x >> 6;
    #pragma unroll
    for (int i = 0; i < 16; i++) {
        int k = i * 4 + ty;
        tl[k][tx] = w[(long)(tk * 64 + k) * 1024 + tj * 64 + tx];
    }
    __syncthreads();
    #pragma unroll
    for (int i = 0; i < 16; i++) {
        int j = i * 4 + ty;
        out[(long)(gate * 1024 + tj * 64 + j) * 1024 + tk * 64 + tx] = f2bf(tl[tx][j]);
    }
}

// ---------------------------------------------------------------------------
__global__ __launch_bounds__(256) void pack_misc(
    const float* __restrict__ bi0, const float* __restrict__ bh0,
    const float* __restrict__ bi1, const float* __restrict__ bh1,
    const float* __restrict__ bi2, const float* __restrict__ bh2,
    const float* __restrict__ bi3, const float* __restrict__ bh3,
    float* __restrict__ bias, unsigned int* __restrict__ hbuf_u,
    unsigned int* __restrict__ flags)
{
    int idx = blockIdx.x * 256 + threadIdx.x;   // grid 256x256 = 65536
    hbuf_u[idx] = 0u;                            // 65536 u32 = 262144 B (both phases)
    if (idx < 4096) {
        int g = idx >> 10, j = idx & 1023;
        const float* bi = (g == 0) ? bi0 : (g == 1) ? bi1 : (g == 2) ? bi2 : bi3;
        const float* bh = (g == 0) ? bh0 : (g == 1) ? bh1 : (g == 2) ? bh2 : bh3;
        bias[idx] = bi[j] + bh[j];
    }
    if (idx < 256) flags[idx] = 0u;              // 4 groups x 64 WG epoch flags
}

// ---------------------------------------------------------------------------
// x_proj GEMM: x[32768][1024] @ Wi[1024][4096] -> xp[b*512+t][h][gate] bf16
// (gate-interleaved so the scan reads 4 gates with one 8B load).
__global__ __launch_bounds__(256, 2) void gemm_xproj(
    const float* __restrict__ x, const unsigned short* __restrict__ wiT,
    unsigned short* __restrict__ xp)
{
    __shared__ unsigned short sA[128 * 72];   // [m][k], stride 72 bf16 (pad 16B)
    __shared__ unsigned short sB[128 * 72];   // [n][k] (WiT already n-major)
    int bid = blockIdx.x;
    int mt = bid >> 5, nt = bid & 31;
    long m0 = (long)mt * 128;
    int n0 = nt * 128;
    int tid = threadIdx.x;
    int lane = tid & 63, wv = tid >> 6;
    int quad = lane >> 4, l15 = lane & 15;
    int wm = wv & 1, wn = wv >> 1;

    f32x4 acc[4][4];
    #pragma unroll
    for (int a = 0; a < 4; a++)
        #pragma unroll
        for (int b = 0; b < 4; b++)
            acc[a][b] = (f32x4){0.f, 0.f, 0.f, 0.f};

    for (int kb = 0; kb < 16; kb++) {
        int k0 = kb * 64;
        #pragma unroll
        for (int i = 0; i < 8; i++) {
            int ch = tid + i * 256;
            int row = ch >> 4, q = ch & 15;
            float4 v = *(const float4*)&x[(m0 + row) * 1024 + k0 + q * 4];
            uint2 p;
            p.x = (unsigned int)f2bf(v.x) | ((unsigned int)f2bf(v.y) << 16);
            p.y = (unsigned int)f2bf(v.z) | ((unsigned int)f2bf(v.w) << 16);
            *(uint2*)&sA[row * 72 + q * 4] = p;
        }
        #pragma unroll
        for (int i = 0; i < 4; i++) {
            int ch = tid + i * 256;
            int row = ch >> 3, q = ch & 7;
            uint4 v = *(const uint4*)&wiT[(long)(n0 + row) * 1024 + k0 + q * 8];
            *(uint4*)&sB[row * 72 + q * 8] = v;
        }
        __syncthreads();
        #pragma unroll
        for (int ks = 0; ks < 2; ks++) {
            bf16x8 af[4], bfr[4];
            #pragma unroll
            for (int mi2 = 0; mi2 < 4; mi2++)
                af[mi2] = *(const bf16x8*)&sA[(wm * 64 + mi2 * 16 + l15) * 72 + ks * 32 + quad * 8];
            #pragma unroll
            for (int ni = 0; ni < 4; ni++)
                bfr[ni] = *(const bf16x8*)&sB[(wn * 64 + ni * 16 + l15) * 72 + ks * 32 + quad * 8];
            #pragma unroll
            for (int mi2 = 0; mi2 < 4; mi2++)
                #pragma unroll
                for (int ni = 0; ni < 4; ni++)
                    acc[mi2][ni] = __builtin_amdgcn_mfma_f32_16x16x32_bf16(
                        af[mi2], bfr[ni], acc[mi2][ni], 0, 0, 0);
        }
        __syncthreads();
    }
    // epilogue: C rows = quad*4+r, cols = l15; scatter by gate: xp[m][h][gate]
    #pragma unroll
    for (int mi2 = 0; mi2 < 4; mi2++)
        #pragma unroll
        for (int ni = 0; ni < 4; ni++)
            #pragma unroll
            for (int r = 0; r < 4; r++) {
                long row = m0 + wm * 64 + mi2 * 16 + quad * 4 + r;
                int col = n0 + wn * 64 + ni * 16 + l15;
                int h = col & 1023, gate = col >> 10;
                xp[row * 4096 + h * 4 + gate] = f2bf(acc[mi2][ni][r]);
            }
}

// ---------------------------------------------------------------------------
// Persistent LSTM scan. 256 blocks x 256 threads.
// group g = bid/64 (batch rows 16g..16g+15), slice s = bid%64 (h cols 16s..16s+15)
// wave w = gate w. Wh B-fragments register-resident.
__global__ __launch_bounds__(256, 2) void lstm_scan(
    const unsigned short* __restrict__ xp, const unsigned short* __restrict__ whT,
    const float* __restrict__ bias, unsigned short* __restrict__ hbuf,
    unsigned int* __restrict__ flags, float* __restrict__ out)
{
    __shared__ unsigned short hl[16 * 1032];  // h tile [16][1024], stride 1032 (pad 16B)
    __shared__ float xch[4][16][16];          // gate exchange

    int bid = blockIdx.x;
    int g = bid >> 6, s = bid & 63;
    int tid = threadIdx.x;
    int lane = tid & 63, wv = tid >> 6;
    int quad = lane >> 4, l15 = lane & 15;

    // preload Wh fragments: B[k=kk*32+quad*8+j][n=l15] from WhT row (gate,col)
    bf16x8 bfrag[32];
    {
        const unsigned short* bp = whT + (long)(wv * 1024 + s * 16 + l15) * 1024 + quad * 8;
        #pragma unroll
        for (int kk = 0; kk < 32; kk++)
            bfrag[kk] = *(const bf16x8*)(bp + kk * 32);
    }

    int row = tid >> 4, col = tid & 15;       // elementwise ownership
    float b4[4];
    #pragma unroll
    for (int gg = 0; gg < 4; gg++) b4[gg] = bias[gg * 1024 + s * 16 + col];

    float c = 0.f;
    const unsigned int* myflags = flags + g * 64 + lane;   // one flag per lane
    unsigned int* myflag = flags + g * 64 + s;
    const char* hb0 = (const char*)(hbuf + g * 16 * 1024);
    const char* hb1 = (const char*)(hbuf + 4 * 16 * 1024 + g * 16 * 1024);
    unsigned short* hw0 = hbuf + g * 16 * 1024;
    unsigned short* hw1 = hbuf + 4 * 16 * 1024 + g * 16 * 1024;

    for (int t = 0; t < 512; t++) {
        // x_proj prefetch: one 8B load = all 4 gates for (batch,col). Issued
        // before the poll so its latency hides behind the wait.
        const unsigned short* xr = xp + ((long)(g * 16 + row) * 512 + t) * 4096
                                      + (s * 16 + col) * 4;
        uint2 xg = *(const uint2*)xr;
        float xpi = bf2f((unsigned short)(xg.x & 0xFFFF));
        float xpf = bf2f((unsigned short)(xg.x >> 16));
        float xpg = bf2f((unsigned short)(xg.y & 0xFFFF));
        float xpo = bf2f((unsigned short)(xg.y >> 16));

        // wait for all 64 producer WGs of this group to publish h(t):
        // each lane owns one flag -> one coalesced 256B wave-load per poll.
        if (t > 0) {
            while (true) {
                unsigned int f = __hip_atomic_load(myflags, __ATOMIC_RELAXED,
                                                   __HIP_MEMORY_SCOPE_AGENT);
                if (__all((int)(f >= (unsigned int)t))) break;
                __builtin_amdgcn_s_sleep(1);
            }
        }

        // stage h(t) 32KB -> LDS via 16B cache-bypassing loads (8 per thread)
        const char* hsrc = (t & 1) ? hb1 : hb0;
        uint4v hv[8];
        #pragma unroll
        for (int i = 0; i < 8; i++) {
            int ch = tid + i * 256;                // 2048 chunks of 16B
            int r2 = ch >> 7, off = ch & 127;
            const void* p = hsrc + r2 * 2048 + off * 16;
            asm volatile("global_load_dwordx4 %0, %1, off sc0 sc1"
                         : "=v"(hv[i]) : "v"(p) : "memory");
        }
        asm volatile("s_waitcnt vmcnt(0)" ::: "memory");
        #pragma unroll
        for (int i = 0; i < 8; i++) {
            int ch = tid + i * 256;
            int r2 = ch >> 7, off = ch & 127;
            *(uint4v*)&hl[r2 * 1032 + off * 8] = hv[i];
        }
        __syncthreads();

        // gate tile for this wave: 16x16, K=1024
        f32x4 acc = {0.f, 0.f, 0.f, 0.f};
        #pragma unroll
        for (int kk = 0; kk < 32; kk++) {
            bf16x8 af = *(const bf16x8*)&hl[l15 * 1032 + kk * 32 + quad * 8];
            acc = __builtin_amdgcn_mfma_f32_16x16x32_bf16(af, bfrag[kk], acc, 0, 0, 0);
        }
        #pragma unroll
        for (int r = 0; r < 4; r++)
            xch[wv][quad * 4 + r][l15] = acc[r];
        __syncthreads();

        // elementwise LSTM cell
        float gi = xch[0][row][col] + xpi + b4[0];
        float gf = xch[1][row][col] + xpf + b4[1];
        float gg_ = xch[2][row][col] + xpg + b4[2];
        float go = xch[3][row][col] + xpo + b4[3];
        float iv = 1.f / (1.f + __expf(-gi));
        float fv = 1.f / (1.f + __expf(-gf));
        float gv = 1.f - 2.f / (__expf(2.f * gg_) + 1.f);   // tanh
        float ov = 1.f / (1.f + __expf(-go));
        c = c * fv + iv * gv;
        float h = ov * (1.f - 2.f / (__expf(2.f * c) + 1.f));

        if (t == 511) {
            out[(g * 16 + row) * 1024 + s * 16 + col] = h;
            out[65536 + (g * 16 + row) * 1024 + s * 16 + col] = c;
        } else {
            // publish h slice write-through (visible at MALL once retired)
            unsigned short* hdst = (t & 1) ? hw0 : hw1;
            __hip_atomic_store(&hdst[row * 1024 + s * 16 + col], f2bf(h),
                               __ATOMIC_RELAXED, __HIP_MEMORY_SCOPE_AGENT);
            // __syncthreads: each wave drains vmcnt(0) before s_barrier, so after
            // the barrier ALL h stores of this WG are at the coherence point.
            __syncthreads();
            if (tid == 0)
                __hip_atomic_store(myflag, (unsigned int)(t + 1),
                                   __ATOMIC_RELAXED, __HIP_MEMORY_SCOPE_AGENT);
            // no trailing barrier: next-iter poll is per-wave.
        }
    }
}

// ---------------------------------------------------------------------------
extern "C" void kernel_launch(void* const* d_in, const int* in_sizes, int n_in,
                              void* d_out, int out_size, void* d_ws, size_t ws_size,
                              hipStream_t stream)
{
    const float* x    = (const float*)d_in[0];
    const float* w_ii = (const float*)d_in[1];
    const float* b_ii = (const float*)d_in[2];
    const float* w_hi = (const float*)d_in[3];
    const float* b_hi = (const float*)d_in[4];
    const float* w_if = (const float*)d_in[5];
    const float* b_if = (const float*)d_in[6];
    const float* w_hf = (const float*)d_in[7];
    const float* b_hf = (const float*)d_in[8];
    const float* w_ig = (const float*)d_in[9];
    const float* b_ig = (const float*)d_in[10];
    const float* w_hg = (const float*)d_in[11];
    const float* b_hg = (const float*)d_in[12];
    const float* w_io = (const float*)d_in[13];
    const float* b_io = (const float*)d_in[14];
    const float* w_ho = (const float*)d_in[15];
    const float* b_ho = (const float*)d_in[16];

    // Workspace layout. Total = 285,493,248 B.
    const size_t OFF_XPJ  = 0;                       // 268,435,456 B
    const size_t OFF_WIT  = 268435456;               //   8,388,608 B
    const size_t OFF_WHT  = 276824064;               //   8,388,608 B
    const size_t OFF_BIAS = 285212672;               //      16,384 B
    const size_t OFF_HBUF = 285229056;               //     262,144 B
    const size_t OFF_FLG  = 285491200;               //       2,048 B
    const size_t NEEDED   = 285493248;
    if (ws_size < NEEDED) return;

    char* ws = (char*)d_ws;
    unsigned short* xpj      = (unsigned short*)(ws + OFF_XPJ);
    unsigned short* wiT      = (unsigned short*)(ws + OFF_WIT);
    unsigned short* whT      = (unsigned short*)(ws + OFF_WHT);
    float*          bias     = (float*)(ws + OFF_BIAS);
    unsigned short* hbuf     = (unsigned short*)(ws + OFF_HBUF);
    unsigned int*   flags    = (unsigned int*)(ws + OFF_FLG);

    pack_wT<<<2048, 256, 0, stream>>>(w_ii, w_if, w_ig, w_io,
                                      w_hi, w_hf, w_hg, w_ho, wiT, whT);
    pack_misc<<<256, 256, 0, stream>>>(b_ii, b_hi, b_if, b_hf, b_ig, b_hg, b_io, b_ho,
                                       bias, (unsigned int*)hbuf, flags);
    gemm_xproj<<<8192, 256, 0, stream>>>(x, wiT, xpj);
    lstm_scan<<<256, 256, 0, stream>>>(xpj, whT, bias, hbuf, flags, (float*)d_out);
}